// Round 1
// baseline (255.515 us; speedup 1.0000x reference)
//
#include <hip/hip_runtime.h>

typedef unsigned short u16;
typedef __attribute__((ext_vector_type(8))) short bf16x8;
typedef __attribute__((ext_vector_type(4))) float f32x4;

#define MFMA16 __builtin_amdgcn_mfma_f32_16x16x32_bf16

__device__ __forceinline__ u16 f2b(float f) {
  unsigned u = __builtin_bit_cast(unsigned, f);
  u = (u + 0x7fffu + ((u >> 16) & 1u)) >> 16;
  return (u16)u;
}

__device__ __forceinline__ void gload_lds16(const u16* g, u16* l) {
  __builtin_amdgcn_global_load_lds((const __attribute__((address_space(1))) void*)g,
                                   (__attribute__((address_space(3))) void*)l, 16, 0, 0);
}

// ---- f32 -> bf16 elementwise (4 per thread) ----
__global__ void cvt_bf16(const float* __restrict__ in, u16* __restrict__ out, int n4) {
  int i = blockIdx.x * blockDim.x + threadIdx.x;
  if (i >= n4) return;
  float4 v = reinterpret_cast<const float4*>(in)[i];
  ushort4 o = make_ushort4(f2b(v.x), f2b(v.y), f2b(v.z), f2b(v.w));
  reinterpret_cast<ushort4*>(out)[i] = o;
}

// ---- weight transpose+convert: W[k][n] f32 -> Wt[n][k] bf16 ----
__global__ void wtrans(const float* __restrict__ w0, const float* __restrict__ w1,
                       const float* __restrict__ w2, const float* __restrict__ w3,
                       u16* __restrict__ o0, u16* __restrict__ o1,
                       u16* __restrict__ o2, u16* __restrict__ o3) {
  const float* src = blockIdx.z == 0 ? w0 : blockIdx.z == 1 ? w1 : blockIdx.z == 2 ? w2 : w3;
  u16* dst = blockIdx.z == 0 ? o0 : blockIdx.z == 1 ? o1 : blockIdx.z == 2 ? o2 : o3;
  __shared__ float t[64][65];
  const int tid = threadIdx.x;
  const int r0 = blockIdx.y * 64, c0 = blockIdx.x * 64;
  #pragma unroll
  for (int it = 0; it < 4; ++it) {
    int row = it * 16 + (tid >> 4);
    int col = (tid & 15) * 4;
    float4 v = *reinterpret_cast<const float4*>(&src[(size_t)(r0 + row) * 1024 + c0 + col]);
    t[row][col] = v.x; t[row][col + 1] = v.y; t[row][col + 2] = v.z; t[row][col + 3] = v.w;
  }
  __syncthreads();
  #pragma unroll
  for (int it = 0; it < 2; ++it) {
    int c = it * 32 + (tid >> 3);
    int r8 = (tid & 7) * 8;
    u16 tmp[8];
    #pragma unroll
    for (int k = 0; k < 8; ++k) tmp[k] = f2b(t[r8 + k][c]);
    uint4 pk;
    pk.x = (unsigned)tmp[0] | ((unsigned)tmp[1] << 16);
    pk.y = (unsigned)tmp[2] | ((unsigned)tmp[3] << 16);
    pk.z = (unsigned)tmp[4] | ((unsigned)tmp[5] << 16);
    pk.w = (unsigned)tmp[6] | ((unsigned)tmp[7] << 16);
    *reinterpret_cast<uint4*>(&dst[(size_t)(c0 + c) * 1024 + r0 + r8]) = pk;
  }
}

// ---- GEMM: C[R=8192,1024] = A[8192,1024] @ Wt^T + bias ----
// MODE 0: bf16 row-major out. MODE 1: bf16 out transposed per head -> Vt[B,H,64,M].
// MODE 2: fp32 row-major out.
template<int MODE>
__global__ __launch_bounds__(256, 2) void gemm_bias(const u16* __restrict__ A,
                                                    const u16* __restrict__ Wt,
                                                    const float* __restrict__ bias,
                                                    void* __restrict__ outp) {
  __shared__ u16 As[2][128 * 32];
  __shared__ u16 Bs[2][128 * 32];
  const int tid = threadIdx.x;
  const int lane = tid & 63;
  const int w = tid >> 6;
  const int wr = w >> 1, wc = w & 1;
  const int l16 = lane & 15, g = lane >> 4;
  const int brow = blockIdx.x * 128, bcol = blockIdx.y * 128;
  f32x4 acc[4][4] = {};

  auto stage = [&](int buf, int kt) {
    #pragma unroll
    for (int it = 0; it < 2; ++it) {
      int chunk = it * 256 + tid;
      int row = chunk >> 2;
      int kk = (chunk & 3) * 8;
      gload_lds16(&A[(size_t)(brow + row) * 1024 + kt * 32 + kk],
                  &As[buf][(it * 256 + w * 64) * 8]);
      gload_lds16(&Wt[(size_t)(bcol + row) * 1024 + kt * 32 + kk],
                  &Bs[buf][(it * 256 + w * 64) * 8]);
    }
  };

  stage(0, 0);
  __syncthreads();
  int cur = 0;
  for (int kt = 0; kt < 32; ++kt) {
    if (kt < 31) stage(cur ^ 1, kt + 1);
    bf16x8 a[4], b[4];
    const int kb = g * 8;
    #pragma unroll
    for (int mi = 0; mi < 4; ++mi)
      a[mi] = *reinterpret_cast<const bf16x8*>(&As[cur][(wr * 64 + mi * 16 + l16) * 32 + kb]);
    #pragma unroll
    for (int ni = 0; ni < 4; ++ni)
      b[ni] = *reinterpret_cast<const bf16x8*>(&Bs[cur][(wc * 64 + ni * 16 + l16) * 32 + kb]);
    #pragma unroll
    for (int mi = 0; mi < 4; ++mi)
      #pragma unroll
      for (int ni = 0; ni < 4; ++ni)
        acc[mi][ni] = MFMA16(a[mi], b[ni], acc[mi][ni], 0, 0, 0);
    __syncthreads();
    cur ^= 1;
  }

  #pragma unroll
  for (int ni = 0; ni < 4; ++ni) {
    const int col = bcol + wc * 64 + ni * 16 + l16;
    const float bz = bias[col];
    #pragma unroll
    for (int mi = 0; mi < 4; ++mi) {
      const int r0 = brow + wr * 64 + mi * 16 + g * 4;
      f32x4 v = acc[mi][ni];
      if constexpr (MODE == 0) {
        u16* o = (u16*)outp;
        #pragma unroll
        for (int j = 0; j < 4; ++j) o[(size_t)(r0 + j) * 1024 + col] = f2b(v[j] + bz);
      } else if constexpr (MODE == 2) {
        float* o = (float*)outp;
        #pragma unroll
        for (int j = 0; j < 4; ++j) o[(size_t)(r0 + j) * 1024 + col] = v[j] + bz;
      } else {
        u16* o = (u16*)outp;
        const int bb = r0 >> 10, m = r0 & 1023;
        const int h = col >> 6, d = col & 63;
        ushort4 pk = make_ushort4(f2b(v[0] + bz), f2b(v[1] + bz), f2b(v[2] + bz), f2b(v[3] + bz));
        *reinterpret_cast<ushort4*>(&o[((size_t)(bb * 16 + h) * 64 + d) * 1024 + m]) = pk;
      }
    }
  }
}

// ---- flash attention: Q[B*N,1024], K[B*M,1024], Vt[B,H,64,M] -> AO[B*N,1024] (all bf16) ----
__global__ __launch_bounds__(256, 2) void attn(const u16* __restrict__ Q, const u16* __restrict__ K,
                                               const u16* __restrict__ Vt, u16* __restrict__ AO) {
  __shared__ u16 Ks[64][72];
  __shared__ u16 Vs[64][72];
  __shared__ u16 Ps[4][16][72];
  const int tid = threadIdx.x, lane = tid & 63, w = tid >> 6;
  const int l16 = lane & 15, g = lane >> 4;
  const int b = blockIdx.z, h = blockIdx.y, qt = blockIdx.x;
  const float cs = 0.125f * 1.44269504089f;  // SCALE * log2(e)

  bf16x8 aq[2];
  {
    const u16* qb = &Q[((size_t)(b * 1024 + qt * 64 + w * 16 + l16)) * 1024 + h * 64 + g * 8];
    aq[0] = *reinterpret_cast<const bf16x8*>(qb);
    aq[1] = *reinterpret_cast<const bf16x8*>(qb + 32);
  }
  f32x4 o[4] = {};
  f32x4 mr = {-1e30f, -1e30f, -1e30f, -1e30f};
  f32x4 lr = {};

  const size_t kg = ((size_t)b * 1024) * 1024 + h * 64;
  const size_t vg = ((size_t)(b * 16 + h) * 64) * 1024;

  for (int kt = 0; kt < 16; ++kt) {
    #pragma unroll
    for (int it = 0; it < 2; ++it) {
      int chunk = it * 256 + tid;
      int row = chunk >> 3;
      int coff = (chunk & 7) * 8;
      *reinterpret_cast<uint4*>(&Ks[row][coff]) =
          *reinterpret_cast<const uint4*>(&K[kg + (size_t)(kt * 64 + row) * 1024 + coff]);
      *reinterpret_cast<uint4*>(&Vs[row][coff]) =
          *reinterpret_cast<const uint4*>(&Vt[vg + (size_t)row * 1024 + kt * 64 + coff]);
    }
    __syncthreads();

    // S = Q K^T (per wave: 16 q-rows x 64 m)
    f32x4 s[4];
    #pragma unroll
    for (int ms = 0; ms < 4; ++ms) {
      f32x4 z = {};
      bf16x8 k0 = *reinterpret_cast<const bf16x8*>(&Ks[ms * 16 + l16][g * 8]);
      bf16x8 k1 = *reinterpret_cast<const bf16x8*>(&Ks[ms * 16 + l16][32 + g * 8]);
      z = MFMA16(aq[0], k0, z, 0, 0, 0);
      z = MFMA16(aq[1], k1, z, 0, 0, 0);
      s[ms] = z;
    }
    #pragma unroll
    for (int ms = 0; ms < 4; ++ms)
      #pragma unroll
      for (int j = 0; j < 4; ++j) s[ms][j] *= cs;

    // online softmax: row stats across the 16 lanes of each group
    f32x4 t;
    #pragma unroll
    for (int j = 0; j < 4; ++j)
      t[j] = fmaxf(fmaxf(s[0][j], s[1][j]), fmaxf(s[2][j], s[3][j]));
    #pragma unroll
    for (int msk = 1; msk < 16; msk <<= 1) {
      #pragma unroll
      for (int j = 0; j < 4; ++j) t[j] = fmaxf(t[j], __shfl_xor(t[j], msk));
    }
    f32x4 al;
    #pragma unroll
    for (int j = 0; j < 4; ++j) {
      float mn = fmaxf(mr[j], t[j]);
      al[j] = exp2f(mr[j] - mn);
      mr[j] = mn;
    }
    f32x4 rs = {};
    #pragma unroll
    for (int ms = 0; ms < 4; ++ms)
      #pragma unroll
      for (int j = 0; j < 4; ++j) {
        float p = exp2f(s[ms][j] - mr[j]);
        s[ms][j] = p;
        rs[j] += p;
      }
    #pragma unroll
    for (int msk = 1; msk < 16; msk <<= 1) {
      #pragma unroll
      for (int j = 0; j < 4; ++j) rs[j] += __shfl_xor(rs[j], msk);
    }
    #pragma unroll
    for (int j = 0; j < 4; ++j) lr[j] = lr[j] * al[j] + rs[j];
    #pragma unroll
    for (int d0 = 0; d0 < 4; ++d0)
      #pragma unroll
      for (int j = 0; j < 4; ++j) o[d0][j] *= al[j];

    // P (C-layout) -> LDS -> A-layout fragments
    #pragma unroll
    for (int ms = 0; ms < 4; ++ms)
      #pragma unroll
      for (int j = 0; j < 4; ++j)
        Ps[w][g * 4 + j][ms * 16 + l16] = f2b(s[ms][j]);
    asm volatile("s_waitcnt lgkmcnt(0)" ::: "memory");
    bf16x8 pa0 = *reinterpret_cast<const bf16x8*>(&Ps[w][l16][g * 8]);
    bf16x8 pa1 = *reinterpret_cast<const bf16x8*>(&Ps[w][l16][32 + g * 8]);
    #pragma unroll
    for (int d0 = 0; d0 < 4; ++d0) {
      bf16x8 v0 = *reinterpret_cast<const bf16x8*>(&Vs[d0 * 16 + l16][g * 8]);
      bf16x8 v1 = *reinterpret_cast<const bf16x8*>(&Vs[d0 * 16 + l16][32 + g * 8]);
      o[d0] = MFMA16(pa0, v0, o[d0], 0, 0, 0);
      o[d0] = MFMA16(pa1, v1, o[d0], 0, 0, 0);
    }
    __syncthreads();
  }

  f32x4 inv;
  #pragma unroll
  for (int j = 0; j < 4; ++j) inv[j] = 1.0f / lr[j];
  #pragma unroll
  for (int d0 = 0; d0 < 4; ++d0)
    #pragma unroll
    for (int j = 0; j < 4; ++j)
      AO[((size_t)(b * 1024 + qt * 64 + w * 16 + g * 4 + j)) * 1024 + h * 64 + d0 * 16 + l16] =
          f2b(o[d0][j] * inv[j]);
}

extern "C" void kernel_launch(void* const* d_in, const int* in_sizes, int n_in,
                              void* d_out, int out_size, void* d_ws, size_t ws_size,
                              hipStream_t stream) {
  const float* x   = (const float*)d_in[0];
  const float* ctx = (const float*)d_in[1];
  const float* Wq  = (const float*)d_in[2];
  const float* bq  = (const float*)d_in[3];
  const float* Wk  = (const float*)d_in[4];
  const float* bk  = (const float*)d_in[5];
  const float* Wv  = (const float*)d_in[6];
  const float* bv  = (const float*)d_in[7];
  const float* Wo  = (const float*)d_in[8];
  const float* bo  = (const float*)d_in[9];
  float* out = (float*)d_out;
  char* ws = (char*)d_ws;

  u16* xb  = (u16*)(ws + (size_t)0);          // 16MB (also reused as AO)
  u16* cb  = (u16*)(ws + ((size_t)16 << 20));
  u16* Qb  = (u16*)(ws + ((size_t)32 << 20));
  u16* Kb  = (u16*)(ws + ((size_t)48 << 20));
  u16* Vt  = (u16*)(ws + ((size_t)64 << 20));
  u16* Wqt = (u16*)(ws + ((size_t)80 << 20));
  u16* Wkt = (u16*)(ws + ((size_t)82 << 20));
  u16* Wvt = (u16*)(ws + ((size_t)84 << 20));
  u16* Wot = (u16*)(ws + ((size_t)86 << 20));

  const int n4 = (8 * 1024 * 1024) / 4;  // 2M float4 groups
  cvt_bf16<<<8192, 256, 0, stream>>>(x, xb, n4);
  cvt_bf16<<<8192, 256, 0, stream>>>(ctx, cb, n4);
  wtrans<<<dim3(16, 16, 4), 256, 0, stream>>>(Wq, Wk, Wv, Wo, Wqt, Wkt, Wvt, Wot);

  dim3 gg(64, 8);
  gemm_bias<0><<<gg, 256, 0, stream>>>(xb, Wqt, bq, (void*)Qb);
  gemm_bias<0><<<gg, 256, 0, stream>>>(cb, Wkt, bk, (void*)Kb);
  gemm_bias<1><<<gg, 256, 0, stream>>>(cb, Wvt, bv, (void*)Vt);
  attn<<<dim3(16, 16, 8), 256, 0, stream>>>(Qb, Kb, Vt, xb /*AO*/);
  gemm_bias<2><<<gg, 256, 0, stream>>>(xb, Wot, bo, (void*)out);
}

// Round 2
// 192.161 us; speedup vs baseline: 1.3297x; 1.3297x over previous
//
#include <hip/hip_runtime.h>

typedef unsigned short u16;
typedef __attribute__((ext_vector_type(8))) short bf16x8;
typedef __attribute__((ext_vector_type(4))) float f32x4;
typedef __attribute__((ext_vector_type(16))) float f32x16;

#define MFMA16 __builtin_amdgcn_mfma_f32_16x16x32_bf16
#define MFMA32 __builtin_amdgcn_mfma_f32_32x32x16_bf16

__device__ __forceinline__ u16 f2b(float f) {
  unsigned u = __builtin_bit_cast(unsigned, f);
  u = (u + 0x7fffu + ((u >> 16) & 1u)) >> 16;
  return (u16)u;
}

__device__ __forceinline__ void gload_lds16(const u16* g, u16* l) {
  __builtin_amdgcn_global_load_lds((const __attribute__((address_space(1))) void*)g,
                                   (__attribute__((address_space(3))) void*)l, 16, 0, 0);
}

// ---- f32 -> bf16 elementwise (4 per thread) ----
__global__ void cvt_bf16(const float* __restrict__ in, u16* __restrict__ out, int n4) {
  int i = blockIdx.x * blockDim.x + threadIdx.x;
  if (i >= n4) return;
  float4 v = reinterpret_cast<const float4*>(in)[i];
  ushort4 o = make_ushort4(f2b(v.x), f2b(v.y), f2b(v.z), f2b(v.w));
  reinterpret_cast<ushort4*>(out)[i] = o;
}

// ---- weight transpose+convert: W[k][n] f32 -> Wt[n][k] bf16 ----
__global__ void wtrans(const float* __restrict__ w0, const float* __restrict__ w1,
                       const float* __restrict__ w2, const float* __restrict__ w3,
                       u16* __restrict__ o0, u16* __restrict__ o1,
                       u16* __restrict__ o2, u16* __restrict__ o3) {
  const float* src = blockIdx.z == 0 ? w0 : blockIdx.z == 1 ? w1 : blockIdx.z == 2 ? w2 : w3;
  u16* dst = blockIdx.z == 0 ? o0 : blockIdx.z == 1 ? o1 : blockIdx.z == 2 ? o2 : o3;
  __shared__ float t[64][65];
  const int tid = threadIdx.x;
  const int r0 = blockIdx.y * 64, c0 = blockIdx.x * 64;
  #pragma unroll
  for (int it = 0; it < 4; ++it) {
    int row = it * 16 + (tid >> 4);
    int col = (tid & 15) * 4;
    float4 v = *reinterpret_cast<const float4*>(&src[(size_t)(r0 + row) * 1024 + c0 + col]);
    t[row][col] = v.x; t[row][col + 1] = v.y; t[row][col + 2] = v.z; t[row][col + 3] = v.w;
  }
  __syncthreads();
  #pragma unroll
  for (int it = 0; it < 2; ++it) {
    int c = it * 32 + (tid >> 3);
    int r8 = (tid & 7) * 8;
    u16 tmp[8];
    #pragma unroll
    for (int k = 0; k < 8; ++k) tmp[k] = f2b(t[r8 + k][c]);
    uint4 pk;
    pk.x = (unsigned)tmp[0] | ((unsigned)tmp[1] << 16);
    pk.y = (unsigned)tmp[2] | ((unsigned)tmp[3] << 16);
    pk.z = (unsigned)tmp[4] | ((unsigned)tmp[5] << 16);
    pk.w = (unsigned)tmp[6] | ((unsigned)tmp[7] << 16);
    *reinterpret_cast<uint4*>(&dst[(size_t)(c0 + c) * 1024 + r0 + r8]) = pk;
  }
}

// ---- GEMM: C[R=8192,1024] = A[8192,1024] @ Wt^T + bias ----
// MODE 0: bf16 row-major. MODE 1: bf16 transposed per head -> Vt[B,H,64,M].
// MODE 2: fp32 row-major. MODE 3: bf16 row-major, scaled by SCALE*log2(e) (for Q).
template<int MODE>
__global__ __launch_bounds__(256, 2) void gemm_bias(const u16* __restrict__ A,
                                                    const u16* __restrict__ Wt,
                                                    const float* __restrict__ bias,
                                                    void* __restrict__ outp) {
  __shared__ u16 As[2][128 * 32];
  __shared__ u16 Bs[2][128 * 32];
  const int tid = threadIdx.x;
  const int lane = tid & 63;
  const int w = tid >> 6;
  const int wr = w >> 1, wc = w & 1;
  const int l16 = lane & 15, g = lane >> 4;
  const int brow = blockIdx.x * 128, bcol = blockIdx.y * 128;
  f32x4 acc[4][4] = {};

  auto stage = [&](int buf, int kt) {
    #pragma unroll
    for (int it = 0; it < 2; ++it) {
      int chunk = it * 256 + tid;
      int row = chunk >> 2;
      int kk = (chunk & 3) * 8;
      gload_lds16(&A[(size_t)(brow + row) * 1024 + kt * 32 + kk],
                  &As[buf][(it * 256 + w * 64) * 8]);
      gload_lds16(&Wt[(size_t)(bcol + row) * 1024 + kt * 32 + kk],
                  &Bs[buf][(it * 256 + w * 64) * 8]);
    }
  };

  stage(0, 0);
  __syncthreads();
  int cur = 0;
  for (int kt = 0; kt < 32; ++kt) {
    if (kt < 31) stage(cur ^ 1, kt + 1);
    bf16x8 a[4], b[4];
    const int kb = g * 8;
    #pragma unroll
    for (int mi = 0; mi < 4; ++mi)
      a[mi] = *reinterpret_cast<const bf16x8*>(&As[cur][(wr * 64 + mi * 16 + l16) * 32 + kb]);
    #pragma unroll
    for (int ni = 0; ni < 4; ++ni)
      b[ni] = *reinterpret_cast<const bf16x8*>(&Bs[cur][(wc * 64 + ni * 16 + l16) * 32 + kb]);
    #pragma unroll
    for (int mi = 0; mi < 4; ++mi)
      #pragma unroll
      for (int ni = 0; ni < 4; ++ni)
        acc[mi][ni] = MFMA16(a[mi], b[ni], acc[mi][ni], 0, 0, 0);
    __syncthreads();
    cur ^= 1;
  }

  const float CS = 0.125f * 1.44269504089f;
  #pragma unroll
  for (int ni = 0; ni < 4; ++ni) {
    const int col = bcol + wc * 64 + ni * 16 + l16;
    const float bz = bias[col];
    #pragma unroll
    for (int mi = 0; mi < 4; ++mi) {
      const int r0 = brow + wr * 64 + mi * 16 + g * 4;
      f32x4 v = acc[mi][ni];
      if constexpr (MODE == 0 || MODE == 3) {
        u16* o = (u16*)outp;
        #pragma unroll
        for (int j = 0; j < 4; ++j) {
          float val = v[j] + bz;
          if constexpr (MODE == 3) val *= CS;
          o[(size_t)(r0 + j) * 1024 + col] = f2b(val);
        }
      } else if constexpr (MODE == 2) {
        float* o = (float*)outp;
        #pragma unroll
        for (int j = 0; j < 4; ++j) o[(size_t)(r0 + j) * 1024 + col] = v[j] + bz;
      } else {
        u16* o = (u16*)outp;
        const int bb = r0 >> 10, m = r0 & 1023;
        const int h = col >> 6, d = col & 63;
        ushort4 pk = make_ushort4(f2b(v[0] + bz), f2b(v[1] + bz), f2b(v[2] + bz), f2b(v[3] + bz));
        *reinterpret_cast<ushort4*>(&o[((size_t)(bb * 16 + h) * 64 + d) * 1024 + m]) = pk;
      }
    }
  }
}

// ---- flash attention v2: swapped 32x32 MFMA, in-register softmax (no max, deferred sum) ----
// Q pre-scaled by SCALE*log2e. Q[B*N,1024], K[B*M,1024], Vt[B,H,64,M] -> AO[B*N,1024] bf16.
// Per block: 4 waves x 32 q-rows = 128 q. KV tiles of 64, K/V in swizzled LDS (dbuf).
__global__ __launch_bounds__(256, 2) void attn2(const u16* __restrict__ Q, const u16* __restrict__ K,
                                                const u16* __restrict__ Vt, u16* __restrict__ AO) {
  __shared__ u16 Ks[2][64 * 64];
  __shared__ u16 Vs[2][64 * 64];
  const int tid = threadIdx.x, lane = tid & 63, w = tid >> 6;
  const int l32 = lane & 31, u = lane >> 5;
  const int b = blockIdx.z, h = blockIdx.y, qt = blockIdx.x;
  const int q0 = qt * 128 + w * 32;
  const int sw = l32 & 7;

  // Q fragments (B-operand): lane holds Q[q0+l32][d = m*16 + 8u + t]
  bf16x8 qf[4];
  {
    const u16* qp = &Q[(size_t)(b * 1024 + q0 + l32) * 1024 + h * 64 + u * 8];
    #pragma unroll
    for (int m = 0; m < 4; ++m) qf[m] = *reinterpret_cast<const bf16x8*>(qp + m * 16);
  }

  f32x16 o0 = {}, o1 = {};
  float lr = 0.f;

  const u16* Kg = K + (size_t)(b * 1024) * 1024 + h * 64;      // rows kv, stride 1024
  const u16* Vg = Vt + (size_t)(b * 16 + h) * 64 * 1024;       // rows d, stride 1024

  // stage tile kt into buf; LDS granule c holds global granule (r=c>>3, (c&7)^(r&7))
  auto stage = [&](int buf, int kt) {
    #pragma unroll
    for (int i = 0; i < 2; ++i) {
      int c = w * 128 + i * 64 + lane;
      int r = c >> 3;
      int gc = ((c & 7) ^ (r & 7)) * 8;
      gload_lds16(&Kg[(size_t)(kt * 64 + r) * 1024 + gc], &Ks[buf][(w * 128 + i * 64) * 8]);
      gload_lds16(&Vg[(size_t)r * 1024 + kt * 64 + gc], &Vs[buf][(w * 128 + i * 64) * 8]);
    }
  };

  stage(0, 0);
  __syncthreads();
  int cur = 0;

  for (int kt = 0; kt < 16; ++kt) {
    if (kt < 15) stage(cur ^ 1, kt + 1);

    // S^T = K_tile (A) x Q (B): s0 = kv rows 0..31, s1 = 32..63.
    // Lane (l32,u) reg r: S[kv=(r&3)+8*(r>>2)+4u (+32*kvb)][q=l32]
    f32x16 s0 = {}, s1 = {};
    #pragma unroll
    for (int m = 0; m < 4; ++m) {
      bf16x8 k0 = *reinterpret_cast<const bf16x8*>(&Ks[cur][(size_t)l32 * 64 + (((2 * m + u) ^ sw) * 8)]);
      bf16x8 k1 = *reinterpret_cast<const bf16x8*>(&Ks[cur][(size_t)(32 + l32) * 64 + (((2 * m + u) ^ sw) * 8)]);
      s0 = MFMA32(k0, qf[m], s0, 0, 0, 0);
      s1 = MFMA32(k1, qf[m], s1, 0, 0, 0);
    }

    // P = exp2(S) (Q pre-scaled); pack to bf16 pairs; accumulate row-sum in-lane.
    unsigned W0[8], W1[8];
    #pragma unroll
    for (int j = 0; j < 8; ++j) {
      const int r = 4 * (j >> 1) + 2 * (j & 1);
      float pa0 = __builtin_amdgcn_exp2f(s0[r]);
      float pb0 = __builtin_amdgcn_exp2f(s0[r + 1]);
      float pa1 = __builtin_amdgcn_exp2f(s1[r]);
      float pb1 = __builtin_amdgcn_exp2f(s1[r + 1]);
      lr += (pa0 + pb0) + (pa1 + pb1);
      asm("v_cvt_pk_bf16_f32 %0, %1, %2" : "=v"(W0[j]) : "v"(pa0), "v"(pb0));
      asm("v_cvt_pk_bf16_f32 %0, %1, %2" : "=v"(W1[j]) : "v"(pa1), "v"(pb1));
    }

    // lane exchange: build PV A-fragments pa[ks] (P[q=l32][kv=ks*16+8u+t])
    unsigned paw[4][4];
    #pragma unroll
    for (int ks = 0; ks < 4; ++ks) {
      const int ksl = ks & 1;
      #pragma unroll
      for (int p = 0; p < 2; ++p) {
        unsigned x = (ks < 2) ? W0[4 * ksl + p] : W1[4 * ksl + p];
        unsigned y = (ks < 2) ? W0[4 * ksl + 2 + p] : W1[4 * ksl + 2 + p];
        asm("v_permlane32_swap_b32 %0, %1" : "+v"(x), "+v"(y));
        paw[ks][p] = x;
        paw[ks][2 + p] = y;
      }
    }

    // O += P x V  (B-frag: V[kv=ks*16+8u+t][d=dblk*32+l32] from Vs[d][kv])
    #pragma unroll
    for (int ks = 0; ks < 4; ++ks) {
      bf16x8 pa;
      #pragma unroll
      for (int f = 0; f < 4; ++f) {
        pa[2 * f] = (short)(paw[ks][f] & 0xffffu);
        pa[2 * f + 1] = (short)(paw[ks][f] >> 16);
      }
      bf16x8 v0 = *reinterpret_cast<const bf16x8*>(&Vs[cur][(size_t)l32 * 64 + (((2 * ks + u) ^ sw) * 8)]);
      bf16x8 v1 = *reinterpret_cast<const bf16x8*>(&Vs[cur][(size_t)(32 + l32) * 64 + (((2 * ks + u) ^ sw) * 8)]);
      o0 = MFMA32(pa, v0, o0, 0, 0, 0);
      o1 = MFMA32(pa, v1, o1, 0, 0, 0);
    }

    __syncthreads();
    cur ^= 1;
  }

  // finish: row sum across the two u-halves, normalize, store.
  float sum = lr + __shfl_xor(lr, 32);
  float rinv = 1.0f / sum;
  u16* aop = &AO[(size_t)(b * 1024 + q0) * 1024 + h * 64 + l32];
  #pragma unroll
  for (int r = 0; r < 16; ++r) {
    const int ql = (r & 3) + 8 * (r >> 2) + 4 * u;
    int ri_i = __builtin_amdgcn_ds_bpermute((ql + (u << 5)) << 2, __builtin_bit_cast(int, rinv));
    float ri = __builtin_bit_cast(float, ri_i);
    aop[(size_t)ql * 1024] = f2b(o0[r] * ri);
    aop[(size_t)ql * 1024 + 32] = f2b(o1[r] * ri);
  }
}

extern "C" void kernel_launch(void* const* d_in, const int* in_sizes, int n_in,
                              void* d_out, int out_size, void* d_ws, size_t ws_size,
                              hipStream_t stream) {
  const float* x   = (const float*)d_in[0];
  const float* ctx = (const float*)d_in[1];
  const float* Wq  = (const float*)d_in[2];
  const float* bq  = (const float*)d_in[3];
  const float* Wk  = (const float*)d_in[4];
  const float* bk  = (const float*)d_in[5];
  const float* Wv  = (const float*)d_in[6];
  const float* bv  = (const float*)d_in[7];
  const float* Wo  = (const float*)d_in[8];
  const float* bo  = (const float*)d_in[9];
  float* out = (float*)d_out;
  char* ws = (char*)d_ws;

  u16* xb  = (u16*)(ws + (size_t)0);          // 16MB (also reused as AO)
  u16* cb  = (u16*)(ws + ((size_t)16 << 20));
  u16* Qb  = (u16*)(ws + ((size_t)32 << 20));
  u16* Kb  = (u16*)(ws + ((size_t)48 << 20));
  u16* Vt  = (u16*)(ws + ((size_t)64 << 20));
  u16* Wqt = (u16*)(ws + ((size_t)80 << 20));
  u16* Wkt = (u16*)(ws + ((size_t)82 << 20));
  u16* Wvt = (u16*)(ws + ((size_t)84 << 20));
  u16* Wot = (u16*)(ws + ((size_t)86 << 20));

  const int n4 = (8 * 1024 * 1024) / 4;
  cvt_bf16<<<8192, 256, 0, stream>>>(x, xb, n4);
  cvt_bf16<<<8192, 256, 0, stream>>>(ctx, cb, n4);
  wtrans<<<dim3(16, 16, 4), 256, 0, stream>>>(Wq, Wk, Wv, Wo, Wqt, Wkt, Wvt, Wot);

  dim3 gg(64, 8);
  gemm_bias<3><<<gg, 256, 0, stream>>>(xb, Wqt, bq, (void*)Qb);   // Q, pre-scaled
  gemm_bias<0><<<gg, 256, 0, stream>>>(cb, Wkt, bk, (void*)Kb);
  gemm_bias<1><<<gg, 256, 0, stream>>>(cb, Wvt, bv, (void*)Vt);
  attn2<<<dim3(8, 16, 8), 256, 0, stream>>>(Qb, Kb, Vt, xb /*AO*/);
  gemm_bias<2><<<gg, 256, 0, stream>>>(xb, Wot, bo, (void*)out);
}

// Round 3
// 171.716 us; speedup vs baseline: 1.4880x; 1.1191x over previous
//
#include <hip/hip_runtime.h>

typedef unsigned short u16;
typedef __attribute__((ext_vector_type(8))) short bf16x8;
typedef __attribute__((ext_vector_type(4))) float f32x4;
typedef __attribute__((ext_vector_type(16))) float f32x16;
typedef __attribute__((ext_vector_type(4))) unsigned u32x4;

#define MFMA16 __builtin_amdgcn_mfma_f32_16x16x32_bf16
#define MFMA32 __builtin_amdgcn_mfma_f32_32x32x16_bf16

__device__ __forceinline__ u16 f2b(float f) {
  unsigned u = __builtin_bit_cast(unsigned, f);
  u = (u + 0x7fffu + ((u >> 16) & 1u)) >> 16;
  return (u16)u;
}

__device__ __forceinline__ void gload_lds16(const u16* g, u16* l) {
  __builtin_amdgcn_global_load_lds((const __attribute__((address_space(1))) void*)g,
                                   (__attribute__((address_space(3))) void*)l, 16, 0, 0);
}

// ---- f32 -> bf16 elementwise, both tensors in one dispatch ----
__global__ void cvt_bf16(const float* __restrict__ a, const float* __restrict__ b,
                         u16* __restrict__ oa, u16* __restrict__ ob, int n4) {
  int i = blockIdx.x * blockDim.x + threadIdx.x;
  if (i >= n4) return;
  const float* in = blockIdx.z ? b : a;
  u16* out = blockIdx.z ? ob : oa;
  float4 v = reinterpret_cast<const float4*>(in)[i];
  ushort4 o = make_ushort4(f2b(v.x), f2b(v.y), f2b(v.z), f2b(v.w));
  reinterpret_cast<ushort4*>(out)[i] = o;
}

// ---- weight transpose+convert: W[k][n] f32 -> Wt[n][k] bf16 ----
__global__ void wtrans(const float* __restrict__ w0, const float* __restrict__ w1,
                       const float* __restrict__ w2, const float* __restrict__ w3,
                       u16* __restrict__ o0, u16* __restrict__ o1,
                       u16* __restrict__ o2, u16* __restrict__ o3) {
  const float* src = blockIdx.z == 0 ? w0 : blockIdx.z == 1 ? w1 : blockIdx.z == 2 ? w2 : w3;
  u16* dst = blockIdx.z == 0 ? o0 : blockIdx.z == 1 ? o1 : blockIdx.z == 2 ? o2 : o3;
  __shared__ float t[64][65];
  const int tid = threadIdx.x;
  const int r0 = blockIdx.y * 64, c0 = blockIdx.x * 64;
  #pragma unroll
  for (int it = 0; it < 4; ++it) {
    int row = it * 16 + (tid >> 4);
    int col = (tid & 15) * 4;
    float4 v = *reinterpret_cast<const float4*>(&src[(size_t)(r0 + row) * 1024 + c0 + col]);
    t[row][col] = v.x; t[row][col + 1] = v.y; t[row][col + 2] = v.z; t[row][col + 3] = v.w;
  }
  __syncthreads();
  #pragma unroll
  for (int it = 0; it < 2; ++it) {
    int c = it * 32 + (tid >> 3);
    int r8 = (tid & 7) * 8;
    u16 tmp[8];
    #pragma unroll
    for (int k = 0; k < 8; ++k) tmp[k] = f2b(t[r8 + k][c]);
    uint4 pk;
    pk.x = (unsigned)tmp[0] | ((unsigned)tmp[1] << 16);
    pk.y = (unsigned)tmp[2] | ((unsigned)tmp[3] << 16);
    pk.z = (unsigned)tmp[4] | ((unsigned)tmp[5] << 16);
    pk.w = (unsigned)tmp[6] | ((unsigned)tmp[7] << 16);
    *reinterpret_cast<uint4*>(&dst[(size_t)(c0 + c) * 1024 + r0 + r8]) = pk;
  }
}

// ---- shared GEMM mainloop: acc = A[brow:+128] x Wt[bcol:+128]^T (K=1024) ----
__device__ __forceinline__ void gemm_core(const u16* __restrict__ A, const u16* __restrict__ Wt,
                                          f32x4 (&acc)[4][4], int brow, int bcol) {
  __shared__ u16 As[2][128 * 32];
  __shared__ u16 Bs[2][128 * 32];
  const int tid = threadIdx.x;
  const int lane = tid & 63;
  const int w = tid >> 6;
  const int wr = w >> 1, wc = w & 1;
  const int l16 = lane & 15, g = lane >> 4;

  auto stage = [&](int buf, int kt) {
    #pragma unroll
    for (int it = 0; it < 2; ++it) {
      int chunk = it * 256 + tid;
      int row = chunk >> 2;
      int kk = (chunk & 3) * 8;
      gload_lds16(&A[(size_t)(brow + row) * 1024 + kt * 32 + kk],
                  &As[buf][(it * 256 + w * 64) * 8]);
      gload_lds16(&Wt[(size_t)(bcol + row) * 1024 + kt * 32 + kk],
                  &Bs[buf][(it * 256 + w * 64) * 8]);
    }
  };

  stage(0, 0);
  __syncthreads();
  int cur = 0;
  for (int kt = 0; kt < 32; ++kt) {
    if (kt < 31) stage(cur ^ 1, kt + 1);
    bf16x8 a[4], b[4];
    const int kb = g * 8;
    #pragma unroll
    for (int mi = 0; mi < 4; ++mi)
      a[mi] = *reinterpret_cast<const bf16x8*>(&As[cur][(wr * 64 + mi * 16 + l16) * 32 + kb]);
    #pragma unroll
    for (int ni = 0; ni < 4; ++ni)
      b[ni] = *reinterpret_cast<const bf16x8*>(&Bs[cur][(wc * 64 + ni * 16 + l16) * 32 + kb]);
    #pragma unroll
    for (int mi = 0; mi < 4; ++mi)
      #pragma unroll
      for (int ni = 0; ni < 4; ++ni)
        acc[mi][ni] = MFMA16(a[mi], b[ni], acc[mi][ni], 0, 0, 0);
    __syncthreads();
    cur ^= 1;
  }
}

// ---- fused Q/K/V projection: blockIdx.z selects {A, W, bias, out, epilogue} ----
// z=0: Q = xb@Wqt+bq, scaled by SCALE*log2e, bf16 row-major.
// z=1: K = cb@Wkt+bk, bf16 row-major.
// z=2: V = cb@Wvt+bv, bf16 transposed per head -> Vt[B,H,64,M].
__global__ __launch_bounds__(256, 2) void gemm_qkv(const u16* __restrict__ xb, const u16* __restrict__ cb,
                                                   const u16* __restrict__ Wqt, const u16* __restrict__ Wkt,
                                                   const u16* __restrict__ Wvt,
                                                   const float* __restrict__ bq, const float* __restrict__ bk,
                                                   const float* __restrict__ bv,
                                                   u16* __restrict__ Qb, u16* __restrict__ Kb,
                                                   u16* __restrict__ Vt) {
  const int z = blockIdx.z;
  const u16* A = z == 0 ? xb : cb;
  const u16* W = z == 0 ? Wqt : z == 1 ? Wkt : Wvt;
  const float* bias = z == 0 ? bq : z == 1 ? bk : bv;
  const int brow = blockIdx.x * 128, bcol = blockIdx.y * 128;
  f32x4 acc[4][4] = {};
  gemm_core(A, W, acc, brow, bcol);

  const int lane = threadIdx.x & 63;
  const int w = threadIdx.x >> 6;
  const int wr = w >> 1, wc = w & 1;
  const int l16 = lane & 15, g = lane >> 4;
  const float CS = 0.125f * 1.44269504089f;
  #pragma unroll
  for (int ni = 0; ni < 4; ++ni) {
    const int col = bcol + wc * 64 + ni * 16 + l16;
    const float bz = bias[col];
    #pragma unroll
    for (int mi = 0; mi < 4; ++mi) {
      const int r0 = brow + wr * 64 + mi * 16 + g * 4;
      f32x4 v = acc[mi][ni];
      if (z == 0) {
        u16* o = Qb;
        #pragma unroll
        for (int j = 0; j < 4; ++j) o[(size_t)(r0 + j) * 1024 + col] = f2b((v[j] + bz) * CS);
      } else if (z == 1) {
        u16* o = Kb;
        #pragma unroll
        for (int j = 0; j < 4; ++j) o[(size_t)(r0 + j) * 1024 + col] = f2b(v[j] + bz);
      } else {
        u16* o = Vt;
        const int bb = r0 >> 10, m = r0 & 1023;
        const int h = col >> 6, d = col & 63;
        ushort4 pk = make_ushort4(f2b(v[0] + bz), f2b(v[1] + bz), f2b(v[2] + bz), f2b(v[3] + bz));
        *reinterpret_cast<ushort4*>(&o[((size_t)(bb * 16 + h) * 64 + d) * 1024 + m]) = pk;
      }
    }
  }
}

// ---- output projection: fp32 out ----
__global__ __launch_bounds__(256, 2) void gemm_o(const u16* __restrict__ A, const u16* __restrict__ Wt,
                                                 const float* __restrict__ bias, float* __restrict__ outp) {
  const int brow = blockIdx.x * 128, bcol = blockIdx.y * 128;
  f32x4 acc[4][4] = {};
  gemm_core(A, Wt, acc, brow, bcol);
  const int lane = threadIdx.x & 63;
  const int w = threadIdx.x >> 6;
  const int wr = w >> 1, wc = w & 1;
  const int l16 = lane & 15, g = lane >> 4;
  #pragma unroll
  for (int ni = 0; ni < 4; ++ni) {
    const int col = bcol + wc * 64 + ni * 16 + l16;
    const float bz = bias[col];
    #pragma unroll
    for (int mi = 0; mi < 4; ++mi) {
      const int r0 = brow + wr * 64 + mi * 16 + g * 4;
      f32x4 v = acc[mi][ni];
      #pragma unroll
      for (int j = 0; j < 4; ++j) outp[(size_t)(r0 + j) * 1024 + col] = v[j] + bz;
    }
  }
}

// ---- flash attention: swapped 32x32 MFMA, in-register softmax, XCD-swizzled grid ----
__global__ __launch_bounds__(256, 2) void attn2(const u16* __restrict__ Q, const u16* __restrict__ K,
                                                const u16* __restrict__ Vt, u16* __restrict__ AO) {
  __shared__ u16 Ks[2][64 * 64];
  __shared__ u16 Vs[2][64 * 64];
  const int tid = threadIdx.x, lane = tid & 63, w = tid >> 6;
  const int l32 = lane & 31, u = lane >> 5;
  // XCD-bijective swizzle: 1024 blocks, 8 XCDs -> XCD x owns virtual ids [x*128, x*128+128)
  // = 16 contiguous (b,h) pairs (K/V slices 4MB/XCD; ~2MB resident) -> L2-local K/V.
  const int id = blockIdx.x;
  const int v = (id & 7) * 128 + (id >> 3);
  const int qt = v & 7, h = (v >> 3) & 15, b = v >> 7;
  const int q0 = qt * 128 + w * 32;
  const int sw = l32 & 7;

  bf16x8 qf[4];
  {
    const u16* qp = &Q[(size_t)(b * 1024 + q0 + l32) * 1024 + h * 64 + u * 8];
    #pragma unroll
    for (int m = 0; m < 4; ++m) qf[m] = *reinterpret_cast<const bf16x8*>(qp + m * 16);
  }

  f32x16 o0 = {}, o1 = {};
  float lr = 0.f;

  const u16* Kg = K + (size_t)(b * 1024) * 1024 + h * 64;      // rows kv, stride 1024
  const u16* Vg = Vt + (size_t)(b * 16 + h) * 64 * 1024;       // rows d, stride 1024

  auto stage = [&](int buf, int kt) {
    #pragma unroll
    for (int i = 0; i < 2; ++i) {
      int c = w * 128 + i * 64 + lane;
      int r = c >> 3;
      int gc = ((c & 7) ^ (r & 7)) * 8;
      gload_lds16(&Kg[(size_t)(kt * 64 + r) * 1024 + gc], &Ks[buf][(w * 128 + i * 64) * 8]);
      gload_lds16(&Vg[(size_t)r * 1024 + kt * 64 + gc], &Vs[buf][(w * 128 + i * 64) * 8]);
    }
  };

  stage(0, 0);
  __syncthreads();
  int cur = 0;

  for (int kt = 0; kt < 16; ++kt) {
    if (kt < 15) stage(cur ^ 1, kt + 1);

    // S^T = K_tile (A) x Q (B)
    f32x16 s0 = {}, s1 = {};
    __builtin_amdgcn_s_setprio(1);
    #pragma unroll
    for (int m = 0; m < 4; ++m) {
      bf16x8 k0 = *reinterpret_cast<const bf16x8*>(&Ks[cur][(size_t)l32 * 64 + (((2 * m + u) ^ sw) * 8)]);
      bf16x8 k1 = *reinterpret_cast<const bf16x8*>(&Ks[cur][(size_t)(32 + l32) * 64 + (((2 * m + u) ^ sw) * 8)]);
      s0 = MFMA32(k0, qf[m], s0, 0, 0, 0);
      s1 = MFMA32(k1, qf[m], s1, 0, 0, 0);
    }
    __builtin_amdgcn_s_setprio(0);

    // P = exp2(S); pack to bf16; accumulate row-sum in-lane.
    unsigned W0[8], W1[8];
    #pragma unroll
    for (int j = 0; j < 8; ++j) {
      const int r = 4 * (j >> 1) + 2 * (j & 1);
      float pa0 = __builtin_amdgcn_exp2f(s0[r]);
      float pb0 = __builtin_amdgcn_exp2f(s0[r + 1]);
      float pa1 = __builtin_amdgcn_exp2f(s1[r]);
      float pb1 = __builtin_amdgcn_exp2f(s1[r + 1]);
      lr += (pa0 + pb0) + (pa1 + pb1);
      asm("v_cvt_pk_bf16_f32 %0, %1, %2" : "=v"(W0[j]) : "v"(pa0), "v"(pb0));
      asm("v_cvt_pk_bf16_f32 %0, %1, %2" : "=v"(W1[j]) : "v"(pa1), "v"(pb1));
    }

    // lane exchange: build PV A-fragments
    unsigned paw[4][4];
    #pragma unroll
    for (int ks = 0; ks < 4; ++ks) {
      const int ksl = ks & 1;
      #pragma unroll
      for (int p = 0; p < 2; ++p) {
        unsigned x = (ks < 2) ? W0[4 * ksl + p] : W1[4 * ksl + p];
        unsigned y = (ks < 2) ? W0[4 * ksl + 2 + p] : W1[4 * ksl + 2 + p];
        asm("v_permlane32_swap_b32 %0, %1" : "+v"(x), "+v"(y));
        paw[ks][p] = x;
        paw[ks][2 + p] = y;
      }
    }

    // O += P x V
    __builtin_amdgcn_s_setprio(1);
    #pragma unroll
    for (int ks = 0; ks < 4; ++ks) {
      bf16x8 pa = __builtin_bit_cast(bf16x8, u32x4{paw[ks][0], paw[ks][1], paw[ks][2], paw[ks][3]});
      bf16x8 v0 = *reinterpret_cast<const bf16x8*>(&Vs[cur][(size_t)l32 * 64 + (((2 * ks + u) ^ sw) * 8)]);
      bf16x8 v1 = *reinterpret_cast<const bf16x8*>(&Vs[cur][(size_t)(32 + l32) * 64 + (((2 * ks + u) ^ sw) * 8)]);
      o0 = MFMA32(pa, v0, o0, 0, 0, 0);
      o1 = MFMA32(pa, v1, o1, 0, 0, 0);
    }
    __builtin_amdgcn_s_setprio(0);

    __syncthreads();
    cur ^= 1;
  }

  float sum = lr + __shfl_xor(lr, 32);
  float rinv = 1.0f / sum;
  u16* aop = &AO[(size_t)(b * 1024 + q0) * 1024 + h * 64 + l32];
  #pragma unroll
  for (int r = 0; r < 16; ++r) {
    const int ql = (r & 3) + 8 * (r >> 2) + 4 * u;
    int ri_i = __builtin_amdgcn_ds_bpermute((ql + (u << 5)) << 2, __builtin_bit_cast(int, rinv));
    float ri = __builtin_bit_cast(float, ri_i);
    aop[(size_t)ql * 1024] = f2b(o0[r] * ri);
    aop[(size_t)ql * 1024 + 32] = f2b(o1[r] * ri);
  }
}

extern "C" void kernel_launch(void* const* d_in, const int* in_sizes, int n_in,
                              void* d_out, int out_size, void* d_ws, size_t ws_size,
                              hipStream_t stream) {
  const float* x   = (const float*)d_in[0];
  const float* ctx = (const float*)d_in[1];
  const float* Wq  = (const float*)d_in[2];
  const float* bq  = (const float*)d_in[3];
  const float* Wk  = (const float*)d_in[4];
  const float* bk  = (const float*)d_in[5];
  const float* Wv  = (const float*)d_in[6];
  const float* bv  = (const float*)d_in[7];
  const float* Wo  = (const float*)d_in[8];
  const float* bo  = (const float*)d_in[9];
  float* out = (float*)d_out;
  char* ws = (char*)d_ws;

  u16* xb  = (u16*)(ws + (size_t)0);          // 16MB (also reused as AO)
  u16* cb  = (u16*)(ws + ((size_t)16 << 20));
  u16* Qb  = (u16*)(ws + ((size_t)32 << 20));
  u16* Kb  = (u16*)(ws + ((size_t)48 << 20));
  u16* Vt  = (u16*)(ws + ((size_t)64 << 20));
  u16* Wqt = (u16*)(ws + ((size_t)80 << 20));
  u16* Wkt = (u16*)(ws + ((size_t)82 << 20));
  u16* Wvt = (u16*)(ws + ((size_t)84 << 20));
  u16* Wot = (u16*)(ws + ((size_t)86 << 20));

  const int n4 = (8 * 1024 * 1024) / 4;
  cvt_bf16<<<dim3(8192, 1, 2), 256, 0, stream>>>(x, ctx, xb, cb, n4);
  wtrans<<<dim3(16, 16, 4), 256, 0, stream>>>(Wq, Wk, Wv, Wo, Wqt, Wkt, Wvt, Wot);

  gemm_qkv<<<dim3(64, 8, 3), 256, 0, stream>>>(xb, cb, Wqt, Wkt, Wvt, bq, bk, bv, Qb, Kb, Vt);
  attn2<<<dim3(1024), 256, 0, stream>>>(Qb, Kb, Vt, xb /*AO*/);
  gemm_o<<<dim3(64, 8), 256, 0, stream>>>(xb, Wot, bo, out);
}

// Round 4
// 152.389 us; speedup vs baseline: 1.6767x; 1.1268x over previous
//
#include <hip/hip_runtime.h>

typedef unsigned short u16;
typedef __attribute__((ext_vector_type(8))) short bf16x8;
typedef __attribute__((ext_vector_type(4))) float f32x4;
typedef __attribute__((ext_vector_type(16))) float f32x16;
typedef __attribute__((ext_vector_type(4))) unsigned u32x4;

#define MFMA16 __builtin_amdgcn_mfma_f32_16x16x32_bf16
#define MFMA32 __builtin_amdgcn_mfma_f32_32x32x16_bf16

__device__ __forceinline__ u16 f2b(float f) {
  unsigned u = __builtin_bit_cast(unsigned, f);
  u = (u + 0x7fffu + ((u >> 16) & 1u)) >> 16;
  return (u16)u;
}

__device__ __forceinline__ void gload_lds16(const u16* g, u16* l) {
  __builtin_amdgcn_global_load_lds((const __attribute__((address_space(1))) void*)g,
                                   (__attribute__((address_space(3))) void*)l, 16, 0, 0);
}

// ---- f32 -> bf16 elementwise, both tensors in one dispatch ----
__global__ void cvt_bf16(const float* __restrict__ a, const float* __restrict__ b,
                         u16* __restrict__ oa, u16* __restrict__ ob, int n4) {
  int i = blockIdx.x * blockDim.x + threadIdx.x;
  if (i >= n4) return;
  const float* in = blockIdx.z ? b : a;
  u16* out = blockIdx.z ? ob : oa;
  float4 v = reinterpret_cast<const float4*>(in)[i];
  ushort4 o = make_ushort4(f2b(v.x), f2b(v.y), f2b(v.z), f2b(v.w));
  reinterpret_cast<ushort4*>(out)[i] = o;
}

// ---- weight transpose+convert: W[k][n] f32 -> Wt[n][k] bf16 ----
__global__ void wtrans(const float* __restrict__ w0, const float* __restrict__ w1,
                       const float* __restrict__ w2, const float* __restrict__ w3,
                       u16* __restrict__ o0, u16* __restrict__ o1,
                       u16* __restrict__ o2, u16* __restrict__ o3) {
  const float* src = blockIdx.z == 0 ? w0 : blockIdx.z == 1 ? w1 : blockIdx.z == 2 ? w2 : w3;
  u16* dst = blockIdx.z == 0 ? o0 : blockIdx.z == 1 ? o1 : blockIdx.z == 2 ? o2 : o3;
  __shared__ float t[64][65];
  const int tid = threadIdx.x;
  const int r0 = blockIdx.y * 64, c0 = blockIdx.x * 64;
  #pragma unroll
  for (int it = 0; it < 4; ++it) {
    int row = it * 16 + (tid >> 4);
    int col = (tid & 15) * 4;
    float4 v = *reinterpret_cast<const float4*>(&src[(size_t)(r0 + row) * 1024 + c0 + col]);
    t[row][col] = v.x; t[row][col + 1] = v.y; t[row][col + 2] = v.z; t[row][col + 3] = v.w;
  }
  __syncthreads();
  #pragma unroll
  for (int it = 0; it < 2; ++it) {
    int c = it * 32 + (tid >> 3);
    int r8 = (tid & 7) * 8;
    u16 tmp[8];
    #pragma unroll
    for (int k = 0; k < 8; ++k) tmp[k] = f2b(t[r8 + k][c]);
    uint4 pk;
    pk.x = (unsigned)tmp[0] | ((unsigned)tmp[1] << 16);
    pk.y = (unsigned)tmp[2] | ((unsigned)tmp[3] << 16);
    pk.z = (unsigned)tmp[4] | ((unsigned)tmp[5] << 16);
    pk.w = (unsigned)tmp[6] | ((unsigned)tmp[7] << 16);
    *reinterpret_cast<uint4*>(&dst[(size_t)(c0 + c) * 1024 + r0 + r8]) = pk;
  }
}

// ---- shared GEMM mainloop, BK=64 (split-k LDS layout [ks][128][32]) ----
// smem: u16[32768] = 64KB. As buf b at b*8192, Bs at 16384 + b*8192.
// Logical As[ks][row][k'] at off ks*4096 + row*32 + k'. 32 MFMA per barrier-pair.
__device__ __forceinline__ void gemm_core(const u16* __restrict__ A, const u16* __restrict__ Wt,
                                          f32x4 (&acc)[4][4], int brow, int bcol,
                                          u16* __restrict__ smem) {
  const int tid = threadIdx.x;
  const int lane = tid & 63;
  const int w = tid >> 6;
  const int wr = w >> 1, wc = w & 1;
  const int l16 = lane & 15, g = lane >> 4;

  auto stage = [&](int buf, int kt) {
    #pragma unroll
    for (int it = 0; it < 4; ++it) {
      int c = it * 256 + tid;
      int row = (c >> 2) & 127;
      int ks = c >> 9;
      int k8 = c & 3;
      const size_t gofs = (size_t)kt * 64 + ks * 32 + k8 * 8;
      gload_lds16(&A[(size_t)(brow + row) * 1024 + gofs],
                  &smem[buf * 8192 + (it * 256 + w * 64) * 8]);
      gload_lds16(&Wt[(size_t)(bcol + row) * 1024 + gofs],
                  &smem[16384 + buf * 8192 + (it * 256 + w * 64) * 8]);
    }
  };

  stage(0, 0);
  __syncthreads();
  int cur = 0;
  for (int kt = 0; kt < 16; ++kt) {
    if (kt < 15) stage(cur ^ 1, kt + 1);
    const u16* As = &smem[cur * 8192];
    const u16* Bs = &smem[16384 + cur * 8192];
    #pragma unroll
    for (int ks = 0; ks < 2; ++ks) {
      bf16x8 a[4], b[4];
      const int kb = ks * 4096 + g * 8;
      #pragma unroll
      for (int mi = 0; mi < 4; ++mi)
        a[mi] = *reinterpret_cast<const bf16x8*>(&As[kb + (wr * 64 + mi * 16 + l16) * 32]);
      #pragma unroll
      for (int ni = 0; ni < 4; ++ni)
        b[ni] = *reinterpret_cast<const bf16x8*>(&Bs[kb + (wc * 64 + ni * 16 + l16) * 32]);
      #pragma unroll
      for (int mi = 0; mi < 4; ++mi)
        #pragma unroll
        for (int ni = 0; ni < 4; ++ni)
          acc[mi][ni] = MFMA16(a[mi], b[ni], acc[mi][ni], 0, 0, 0);
    }
    __syncthreads();
    cur ^= 1;
  }
}

// ---- fused Q/K/V projection: blockIdx.z selects {A, W, bias, out, epilogue} ----
// z=0: Q = xb@Wqt+bq, scaled by SCALE*log2e, bf16 row-major.
// z=1: K = cb@Wkt+bk, bf16 row-major.
// z=2: V = cb@Wvt+bv, bf16 transposed per head -> Vt[B,H,64,M] (LDS-staged coalesced write).
__global__ __launch_bounds__(256, 2) void gemm_qkv(const u16* __restrict__ xb, const u16* __restrict__ cb,
                                                   const u16* __restrict__ Wqt, const u16* __restrict__ Wkt,
                                                   const u16* __restrict__ Wvt,
                                                   const float* __restrict__ bq, const float* __restrict__ bk,
                                                   const float* __restrict__ bv,
                                                   u16* __restrict__ Qb, u16* __restrict__ Kb,
                                                   u16* __restrict__ Vt) {
  __shared__ u16 smem[32768];
  const int z = blockIdx.z;
  const u16* A = z == 0 ? xb : cb;
  const u16* W = z == 0 ? Wqt : z == 1 ? Wkt : Wvt;
  const float* bias = z == 0 ? bq : z == 1 ? bk : bv;
  const int brow = blockIdx.x * 128, bcol = blockIdx.y * 128;
  f32x4 acc[4][4] = {};
  gemm_core(A, W, acc, brow, bcol, smem);

  const int lane = threadIdx.x & 63;
  const int w = threadIdx.x >> 6;
  const int wr = w >> 1, wc = w & 1;
  const int l16 = lane & 15, g = lane >> 4;
  const float CS = 0.125f * 1.44269504089f;

  if (z < 2) {
    u16* o = z == 0 ? Qb : Kb;
    #pragma unroll
    for (int ni = 0; ni < 4; ++ni) {
      const int col = bcol + wc * 64 + ni * 16 + l16;
      const float bz = bias[col];
      #pragma unroll
      for (int mi = 0; mi < 4; ++mi) {
        const int r0 = brow + wr * 64 + mi * 16 + g * 4;
        f32x4 v = acc[mi][ni];
        #pragma unroll
        for (int j = 0; j < 4; ++j) {
          float val = v[j] + bz;
          if (z == 0) val *= CS;
          o[(size_t)(r0 + j) * 1024 + col] = f2b(val);
        }
      }
    }
  } else {
    // V: per-wave 64x64 transpose through LDS -> 16B-coalesced writes along m.
    u16* T = &smem[w * 4608];  // 64 rows (d) x 72 (m, padded: 144B row = 16B-aligned)
    #pragma unroll
    for (int ni = 0; ni < 4; ++ni) {
      const int col = bcol + wc * 64 + ni * 16 + l16;
      const float bz = bias[col];
      #pragma unroll
      for (int mi = 0; mi < 4; ++mi) {
        f32x4 v = acc[mi][ni];
        #pragma unroll
        for (int j = 0; j < 4; ++j)
          T[(ni * 16 + l16) * 72 + mi * 16 + g * 4 + j] = f2b(v[j] + bz);
      }
    }
    // wave-local transpose readback (compiler inserts lgkmcnt between ds ops)
    const int h = (bcol + wc * 64) >> 6;
    const int m0 = brow + wr * 64;
    const int bb = m0 >> 10, mloc = m0 & 1023;
    u16* vb = &Vt[((size_t)(bb * 16 + h) * 64) * 1024 + mloc];
    #pragma unroll
    for (int it = 0; it < 8; ++it) {
      const int d = it * 8 + (lane >> 3);
      const int m8 = (lane & 7) * 8;
      bf16x8 val = *reinterpret_cast<const bf16x8*>(&T[d * 72 + m8]);
      *reinterpret_cast<bf16x8*>(&vb[(size_t)d * 1024 + m8]) = val;
    }
  }
}

// ---- output projection: fp32 out ----
__global__ __launch_bounds__(256, 2) void gemm_o(const u16* __restrict__ A, const u16* __restrict__ Wt,
                                                 const float* __restrict__ bias, float* __restrict__ outp) {
  __shared__ u16 smem[32768];
  const int brow = blockIdx.x * 128, bcol = blockIdx.y * 128;
  f32x4 acc[4][4] = {};
  gemm_core(A, Wt, acc, brow, bcol, smem);
  const int lane = threadIdx.x & 63;
  const int w = threadIdx.x >> 6;
  const int wr = w >> 1, wc = w & 1;
  const int l16 = lane & 15, g = lane >> 4;
  #pragma unroll
  for (int ni = 0; ni < 4; ++ni) {
    const int col = bcol + wc * 64 + ni * 16 + l16;
    const float bz = bias[col];
    #pragma unroll
    for (int mi = 0; mi < 4; ++mi) {
      const int r0 = brow + wr * 64 + mi * 16 + g * 4;
      f32x4 v = acc[mi][ni];
      #pragma unroll
      for (int j = 0; j < 4; ++j) outp[(size_t)(r0 + j) * 1024 + col] = v[j] + bz;
    }
  }
}

// ---- flash attention: swapped 32x32 MFMA, in-register softmax, XCD-swizzled grid ----
__global__ __launch_bounds__(256, 2) void attn2(const u16* __restrict__ Q, const u16* __restrict__ K,
                                                const u16* __restrict__ Vt, u16* __restrict__ AO) {
  __shared__ u16 Ks[2][64 * 64];
  __shared__ u16 Vs[2][64 * 64];
  const int tid = threadIdx.x, lane = tid & 63, w = tid >> 6;
  const int l32 = lane & 31, u = lane >> 5;
  // XCD-bijective swizzle: 1024 blocks, 8 XCDs -> XCD x owns virtual ids [x*128, x*128+128)
  const int id = blockIdx.x;
  const int v = (id & 7) * 128 + (id >> 3);
  const int qt = v & 7, h = (v >> 3) & 15, b = v >> 7;
  const int q0 = qt * 128 + w * 32;
  const int sw = l32 & 7;

  bf16x8 qf[4];
  {
    const u16* qp = &Q[(size_t)(b * 1024 + q0 + l32) * 1024 + h * 64 + u * 8];
    #pragma unroll
    for (int m = 0; m < 4; ++m) qf[m] = *reinterpret_cast<const bf16x8*>(qp + m * 16);
  }

  f32x16 o0 = {}, o1 = {};
  float lr = 0.f;

  const u16* Kg = K + (size_t)(b * 1024) * 1024 + h * 64;
  const u16* Vg = Vt + (size_t)(b * 16 + h) * 64 * 1024;

  auto stage = [&](int buf, int kt) {
    #pragma unroll
    for (int i = 0; i < 2; ++i) {
      int c = w * 128 + i * 64 + lane;
      int r = c >> 3;
      int gc = ((c & 7) ^ (r & 7)) * 8;
      gload_lds16(&Kg[(size_t)(kt * 64 + r) * 1024 + gc], &Ks[buf][(w * 128 + i * 64) * 8]);
      gload_lds16(&Vg[(size_t)r * 1024 + kt * 64 + gc], &Vs[buf][(w * 128 + i * 64) * 8]);
    }
  };

  stage(0, 0);
  __syncthreads();
  int cur = 0;

  for (int kt = 0; kt < 16; ++kt) {
    if (kt < 15) stage(cur ^ 1, kt + 1);

    // S^T = K_tile (A) x Q (B)
    f32x16 s0 = {}, s1 = {};
    __builtin_amdgcn_s_setprio(1);
    #pragma unroll
    for (int m = 0; m < 4; ++m) {
      bf16x8 k0 = *reinterpret_cast<const bf16x8*>(&Ks[cur][(size_t)l32 * 64 + (((2 * m + u) ^ sw) * 8)]);
      bf16x8 k1 = *reinterpret_cast<const bf16x8*>(&Ks[cur][(size_t)(32 + l32) * 64 + (((2 * m + u) ^ sw) * 8)]);
      s0 = MFMA32(k0, qf[m], s0, 0, 0, 0);
      s1 = MFMA32(k1, qf[m], s1, 0, 0, 0);
    }
    __builtin_amdgcn_s_setprio(0);

    // P = exp2(S); pack to bf16; accumulate row-sum in-lane.
    unsigned W0[8], W1[8];
    #pragma unroll
    for (int j = 0; j < 8; ++j) {
      const int r = 4 * (j >> 1) + 2 * (j & 1);
      float pa0 = __builtin_amdgcn_exp2f(s0[r]);
      float pb0 = __builtin_amdgcn_exp2f(s0[r + 1]);
      float pa1 = __builtin_amdgcn_exp2f(s1[r]);
      float pb1 = __builtin_amdgcn_exp2f(s1[r + 1]);
      lr += (pa0 + pb0) + (pa1 + pb1);
      asm("v_cvt_pk_bf16_f32 %0, %1, %2" : "=v"(W0[j]) : "v"(pa0), "v"(pb0));
      asm("v_cvt_pk_bf16_f32 %0, %1, %2" : "=v"(W1[j]) : "v"(pa1), "v"(pb1));
    }

    // lane exchange: build PV A-fragments
    unsigned paw[4][4];
    #pragma unroll
    for (int ks = 0; ks < 4; ++ks) {
      const int ksl = ks & 1;
      #pragma unroll
      for (int p = 0; p < 2; ++p) {
        unsigned x = (ks < 2) ? W0[4 * ksl + p] : W1[4 * ksl + p];
        unsigned y = (ks < 2) ? W0[4 * ksl + 2 + p] : W1[4 * ksl + 2 + p];
        asm("v_permlane32_swap_b32 %0, %1" : "+v"(x), "+v"(y));
        paw[ks][p] = x;
        paw[ks][2 + p] = y;
      }
    }

    // O += P x V
    __builtin_amdgcn_s_setprio(1);
    #pragma unroll
    for (int ks = 0; ks < 4; ++ks) {
      bf16x8 pa = __builtin_bit_cast(bf16x8, u32x4{paw[ks][0], paw[ks][1], paw[ks][2], paw[ks][3]});
      bf16x8 v0 = *reinterpret_cast<const bf16x8*>(&Vs[cur][(size_t)l32 * 64 + (((2 * ks + u) ^ sw) * 8)]);
      bf16x8 v1 = *reinterpret_cast<const bf16x8*>(&Vs[cur][(size_t)(32 + l32) * 64 + (((2 * ks + u) ^ sw) * 8)]);
      o0 = MFMA32(pa, v0, o0, 0, 0, 0);
      o1 = MFMA32(pa, v1, o1, 0, 0, 0);
    }
    __builtin_amdgcn_s_setprio(0);

    __syncthreads();
    cur ^= 1;
  }

  float sum = lr + __shfl_xor(lr, 32);
  float rinv = 1.0f / sum;
  u16* aop = &AO[(size_t)(b * 1024 + q0) * 1024 + h * 64 + l32];
  #pragma unroll
  for (int r = 0; r < 16; ++r) {
    const int ql = (r & 3) + 8 * (r >> 2) + 4 * u;
    int ri_i = __builtin_amdgcn_ds_bpermute((ql + (u << 5)) << 2, __builtin_bit_cast(int, rinv));
    float ri = __builtin_bit_cast(float, ri_i);
    aop[(size_t)ql * 1024] = f2b(o0[r] * ri);
    aop[(size_t)ql * 1024 + 32] = f2b(o1[r] * ri);
  }
}

extern "C" void kernel_launch(void* const* d_in, const int* in_sizes, int n_in,
                              void* d_out, int out_size, void* d_ws, size_t ws_size,
                              hipStream_t stream) {
  const float* x   = (const float*)d_in[0];
  const float* ctx = (const float*)d_in[1];
  const float* Wq  = (const float*)d_in[2];
  const float* bq  = (const float*)d_in[3];
  const float* Wk  = (const float*)d_in[4];
  const float* bk  = (const float*)d_in[5];
  const float* Wv  = (const float*)d_in[6];
  const float* bv  = (const float*)d_in[7];
  const float* Wo  = (const float*)d_in[8];
  const float* bo  = (const float*)d_in[9];
  float* out = (float*)d_out;
  char* ws = (char*)d_ws;

  u16* xb  = (u16*)(ws + (size_t)0);          // 16MB (also reused as AO)
  u16* cb  = (u16*)(ws + ((size_t)16 << 20));
  u16* Qb  = (u16*)(ws + ((size_t)32 << 20));
  u16* Kb  = (u16*)(ws + ((size_t)48 << 20));
  u16* Vt  = (u16*)(ws + ((size_t)64 << 20));
  u16* Wqt = (u16*)(ws + ((size_t)80 << 20));
  u16* Wkt = (u16*)(ws + ((size_t)82 << 20));
  u16* Wvt = (u16*)(ws + ((size_t)84 << 20));
  u16* Wot = (u16*)(ws + ((size_t)86 << 20));

  const int n4 = (8 * 1024 * 1024) / 4;
  cvt_bf16<<<dim3(8192, 1, 2), 256, 0, stream>>>(x, ctx, xb, cb, n4);
  wtrans<<<dim3(16, 16, 4), 256, 0, stream>>>(Wq, Wk, Wv, Wo, Wqt, Wkt, Wvt, Wot);

  gemm_qkv<<<dim3(64, 8, 3), 256, 0, stream>>>(xb, cb, Wqt, Wkt, Wvt, bq, bk, bv, Qb, Kb, Vt);
  attn2<<<dim3(1024), 256, 0, stream>>>(Qb, Kb, Vt, xb /*AO*/);
  gemm_o<<<dim3(64, 8), 256, 0, stream>>>(xb, Wot, bo, out);
}

// Round 5
// 152.268 us; speedup vs baseline: 1.6781x; 1.0008x over previous
//
#include <hip/hip_runtime.h>

typedef unsigned short u16;
typedef __attribute__((ext_vector_type(8))) short bf16x8;
typedef __attribute__((ext_vector_type(4))) float f32x4;
typedef __attribute__((ext_vector_type(16))) float f32x16;
typedef __attribute__((ext_vector_type(4))) unsigned u32x4;

#define MFMA16 __builtin_amdgcn_mfma_f32_16x16x32_bf16
#define MFMA32 __builtin_amdgcn_mfma_f32_32x32x16_bf16

__device__ __forceinline__ u16 f2b(float f) {
  unsigned u = __builtin_bit_cast(unsigned, f);
  u = (u + 0x7fffu + ((u >> 16) & 1u)) >> 16;
  return (u16)u;
}

__device__ __forceinline__ void gload_lds16(const u16* g, u16* l) {
  __builtin_amdgcn_global_load_lds((const __attribute__((address_space(1))) void*)g,
                                   (__attribute__((address_space(3))) void*)l, 16, 0, 0);
}

// ---- fused prep: z<2 -> f32->bf16 convert of x/ctx; z=2 -> weight transpose ----
__global__ void prep(const float* __restrict__ x, const float* __restrict__ ctx,
                     u16* __restrict__ xb, u16* __restrict__ cb,
                     const float* __restrict__ w0, const float* __restrict__ w1,
                     const float* __restrict__ w2, const float* __restrict__ w3,
                     u16* __restrict__ o0, u16* __restrict__ o1,
                     u16* __restrict__ o2, u16* __restrict__ o3) {
  __shared__ float t[64][65];
  const int z = blockIdx.z;
  const int tid = threadIdx.x;
  if (z < 2) {
    int i = blockIdx.x * blockDim.x + tid;
    const float* in = z ? ctx : x;
    u16* out = z ? cb : xb;
    float4 v = reinterpret_cast<const float4*>(in)[i];
    reinterpret_cast<ushort4*>(out)[i] = make_ushort4(f2b(v.x), f2b(v.y), f2b(v.z), f2b(v.w));
    return;
  }
  const int id = blockIdx.x;
  if (id >= 1024) return;
  const int wsel = id >> 8;
  const float* src = wsel == 0 ? w0 : wsel == 1 ? w1 : wsel == 2 ? w2 : w3;
  u16* dst = wsel == 0 ? o0 : wsel == 1 ? o1 : wsel == 2 ? o2 : o3;
  const int r0 = ((id >> 4) & 15) * 64, c0 = (id & 15) * 64;
  #pragma unroll
  for (int it = 0; it < 4; ++it) {
    int row = it * 16 + (tid >> 4);
    int col = (tid & 15) * 4;
    float4 v = *reinterpret_cast<const float4*>(&src[(size_t)(r0 + row) * 1024 + c0 + col]);
    t[row][col] = v.x; t[row][col + 1] = v.y; t[row][col + 2] = v.z; t[row][col + 3] = v.w;
  }
  __syncthreads();
  #pragma unroll
  for (int it = 0; it < 2; ++it) {
    int c = it * 32 + (tid >> 3);
    int r8 = (tid & 7) * 8;
    u16 tmp[8];
    #pragma unroll
    for (int k = 0; k < 8; ++k) tmp[k] = f2b(t[r8 + k][c]);
    uint4 pk;
    pk.x = (unsigned)tmp[0] | ((unsigned)tmp[1] << 16);
    pk.y = (unsigned)tmp[2] | ((unsigned)tmp[3] << 16);
    pk.z = (unsigned)tmp[4] | ((unsigned)tmp[5] << 16);
    pk.w = (unsigned)tmp[6] | ((unsigned)tmp[7] << 16);
    *reinterpret_cast<uint4*>(&dst[(size_t)(c0 + c) * 1024 + r0 + r8]) = pk;
  }
}

// ---- shared GEMM mainloop, BK=64 (split-k LDS layout [ks][128][32]) ----
__device__ __forceinline__ void gemm_core(const u16* __restrict__ A, const u16* __restrict__ Wt,
                                          f32x4 (&acc)[4][4], int brow, int bcol,
                                          u16* __restrict__ smem) {
  const int tid = threadIdx.x;
  const int lane = tid & 63;
  const int w = tid >> 6;
  const int wr = w >> 1, wc = w & 1;
  const int l16 = lane & 15, g = lane >> 4;

  auto stage = [&](int buf, int kt) {
    #pragma unroll
    for (int it = 0; it < 4; ++it) {
      int c = it * 256 + tid;
      int row = (c >> 2) & 127;
      int ks = c >> 9;
      int k8 = c & 3;
      const size_t gofs = (size_t)kt * 64 + ks * 32 + k8 * 8;
      gload_lds16(&A[(size_t)(brow + row) * 1024 + gofs],
                  &smem[buf * 8192 + (it * 256 + w * 64) * 8]);
      gload_lds16(&Wt[(size_t)(bcol + row) * 1024 + gofs],
                  &smem[16384 + buf * 8192 + (it * 256 + w * 64) * 8]);
    }
  };

  stage(0, 0);
  __syncthreads();
  int cur = 0;
  for (int kt = 0; kt < 16; ++kt) {
    if (kt < 15) stage(cur ^ 1, kt + 1);
    const u16* As = &smem[cur * 8192];
    const u16* Bs = &smem[16384 + cur * 8192];
    #pragma unroll
    for (int ks = 0; ks < 2; ++ks) {
      bf16x8 a[4], b[4];
      const int kb = ks * 4096 + g * 8;
      #pragma unroll
      for (int mi = 0; mi < 4; ++mi)
        a[mi] = *reinterpret_cast<const bf16x8*>(&As[kb + (wr * 64 + mi * 16 + l16) * 32]);
      #pragma unroll
      for (int ni = 0; ni < 4; ++ni)
        b[ni] = *reinterpret_cast<const bf16x8*>(&Bs[kb + (wc * 64 + ni * 16 + l16) * 32]);
      #pragma unroll
      for (int mi = 0; mi < 4; ++mi)
        #pragma unroll
        for (int ni = 0; ni < 4; ++ni)
          acc[mi][ni] = MFMA16(a[mi], b[ni], acc[mi][ni], 0, 0, 0);
    }
    __syncthreads();
    cur ^= 1;
  }
}

// ---- fused Q/K/V projection ----
// z=0: Q row-major bf16, pre-scaled by SCALE*log2e.
// z=1: K in attn fragment order Kf[b,h][kt][512 chunks]x16B.
// z=2: V in attn fragment order Vf[b,h][kt][512 chunks]x16B.
// Fragment chunk decode (within a kt tile): c = m2*128 + half*64 + u2*32 + l holds
//   K: K[kv = kt*64 + half*32 + l][hcol = m2*16 + u2*8 .. +8]
//   V: Vt[d = half*32 + l][mcol = kt*64 + m2*16 + u2*8 .. +8]
__global__ __launch_bounds__(256, 2) void gemm_qkv(const u16* __restrict__ xb, const u16* __restrict__ cb,
                                                   const u16* __restrict__ Wqt, const u16* __restrict__ Wkt,
                                                   const u16* __restrict__ Wvt,
                                                   const float* __restrict__ bq, const float* __restrict__ bk,
                                                   const float* __restrict__ bv,
                                                   u16* __restrict__ Qb, u16* __restrict__ Kf,
                                                   u16* __restrict__ Vf) {
  __shared__ u16 smem[32768];
  const int z = blockIdx.z;
  const u16* A = z == 0 ? xb : cb;
  const u16* W = z == 0 ? Wqt : z == 1 ? Wkt : Wvt;
  const float* bias = z == 0 ? bq : z == 1 ? bk : bv;
  const int brow = blockIdx.x * 128, bcol = blockIdx.y * 128;
  f32x4 acc[4][4] = {};
  gemm_core(A, W, acc, brow, bcol, smem);

  const int lane = threadIdx.x & 63;
  const int w = threadIdx.x >> 6;
  const int wr = w >> 1, wc = w & 1;
  const int l16 = lane & 15, g = lane >> 4;
  const float CS = 0.125f * 1.44269504089f;
  u16* T = &smem[w * 5120];  // 64 rows x 80 cols (160B pitch: conflict-free b128 readback)

  if (z < 2) {
    // stage to LDS row-major [row=m-local][col]
    #pragma unroll
    for (int ni = 0; ni < 4; ++ni) {
      const float bz = bias[bcol + wc * 64 + ni * 16 + l16];
      #pragma unroll
      for (int mi = 0; mi < 4; ++mi) {
        f32x4 v = acc[mi][ni];
        #pragma unroll
        for (int j = 0; j < 4; ++j) {
          float val = v[j] + bz;
          if (z == 0) val *= CS;
          T[(mi * 16 + g * 4 + j) * 80 + ni * 16 + l16] = f2b(val);
        }
      }
    }
    const int r0b = brow + wr * 64;
    const int colb = bcol + wc * 64;
    if (z == 0) {
      #pragma unroll
      for (int it = 0; it < 8; ++it) {
        const int rl = it * 8 + (lane >> 3);
        const int c8 = (lane & 7) * 8;
        bf16x8 val = *reinterpret_cast<const bf16x8*>(&T[rl * 80 + c8]);
        *reinterpret_cast<bf16x8*>(&Qb[(size_t)(r0b + rl) * 1024 + colb + c8]) = val;
      }
    } else {
      const int h = colb >> 6;
      const int bb = r0b >> 10;
      const int kt = (r0b & 1023) >> 6;
      u16* kb2 = &Kf[(((size_t)(bb * 16 + h)) * 16 + kt) * 4096];
      #pragma unroll
      for (int it = 0; it < 8; ++it) {
        const int rl = it * 8 + (lane >> 3);
        const int c8 = (lane & 7) * 8;
        bf16x8 val = *reinterpret_cast<const bf16x8*>(&T[rl * 80 + c8]);
        const int chunk = (c8 >> 4) * 128 + (rl >> 5) * 64 + ((c8 >> 3) & 1) * 32 + (rl & 31);
        *reinterpret_cast<bf16x8*>(&kb2[chunk * 8]) = val;
      }
    }
  } else {
    // V: per-wave transpose to T[d-local][m-local], then fragment-order global write
    #pragma unroll
    for (int ni = 0; ni < 4; ++ni) {
      const float bz = bias[bcol + wc * 64 + ni * 16 + l16];
      #pragma unroll
      for (int mi = 0; mi < 4; ++mi) {
        f32x4 v = acc[mi][ni];
        #pragma unroll
        for (int j = 0; j < 4; ++j)
          T[(ni * 16 + l16) * 80 + mi * 16 + g * 4 + j] = f2b(v[j] + bz);
      }
    }
    const int h = (bcol + wc * 64) >> 6;
    const int m0 = brow + wr * 64;
    const int bb = m0 >> 10;
    const int kt = (m0 & 1023) >> 6;
    u16* vb = &Vf[(((size_t)(bb * 16 + h)) * 16 + kt) * 4096];
    #pragma unroll
    for (int it = 0; it < 8; ++it) {
      const int d = it * 8 + (lane >> 3);
      const int m8 = (lane & 7) * 8;
      bf16x8 val = *reinterpret_cast<const bf16x8*>(&T[d * 80 + m8]);
      const int chunk = (m8 >> 4) * 128 + (d >> 5) * 64 + ((m8 >> 3) & 1) * 32 + (d & 31);
      *reinterpret_cast<bf16x8*>(&vb[chunk * 8]) = val;
    }
  }
}

// ---- output projection: fp32 out ----
__global__ __launch_bounds__(256, 2) void gemm_o(const u16* __restrict__ A, const u16* __restrict__ Wt,
                                                 const float* __restrict__ bias, float* __restrict__ outp) {
  __shared__ u16 smem[32768];
  const int brow = blockIdx.x * 128, bcol = blockIdx.y * 128;
  f32x4 acc[4][4] = {};
  gemm_core(A, Wt, acc, brow, bcol, smem);
  const int lane = threadIdx.x & 63;
  const int w = threadIdx.x >> 6;
  const int wr = w >> 1, wc = w & 1;
  const int l16 = lane & 15, g = lane >> 4;
  #pragma unroll
  for (int ni = 0; ni < 4; ++ni) {
    const int col = bcol + wc * 64 + ni * 16 + l16;
    const float bz = bias[col];
    #pragma unroll
    for (int mi = 0; mi < 4; ++mi) {
      const int r0 = brow + wr * 64 + mi * 16 + g * 4;
      f32x4 v = acc[mi][ni];
      #pragma unroll
      for (int j = 0; j < 4; ++j) outp[(size_t)(r0 + j) * 1024 + col] = v[j] + bz;
    }
  }
}

// ---- flash attention: fragment-order K/V (contiguous stage, zero-conflict ds_read) ----
__global__ __launch_bounds__(256, 2) void attn2(const u16* __restrict__ Q, const u16* __restrict__ Kf,
                                                const u16* __restrict__ Vf, u16* __restrict__ AO) {
  __shared__ u16 Ks[2][64 * 64];
  __shared__ u16 Vs[2][64 * 64];
  const int tid = threadIdx.x, lane = tid & 63, w = tid >> 6;
  const int l32 = lane & 31, u = lane >> 5;
  // XCD-bijective swizzle: 1024 blocks, 8 XCDs -> XCD x owns 16 contiguous (b,h) pairs.
  const int id = blockIdx.x;
  const int v = (id & 7) * 128 + (id >> 3);
  const int qt = v & 7, h = (v >> 3) & 15, b = v >> 7;
  const int q0 = qt * 128 + w * 32;

  bf16x8 qf[4];
  {
    const u16* qp = &Q[(size_t)(b * 1024 + q0 + l32) * 1024 + h * 64 + u * 8];
    #pragma unroll
    for (int m = 0; m < 4; ++m) qf[m] = *reinterpret_cast<const bf16x8*>(qp + m * 16);
  }

  f32x16 o0 = {}, o1 = {};
  float lr = 0.f;

  const u16* Kbh = Kf + (size_t)(b * 16 + h) * 65536;  // 16 kt x 4096 u16
  const u16* Vbh = Vf + (size_t)(b * 16 + h) * 65536;

  auto stage = [&](int buf, int kt) {
    #pragma unroll
    for (int it = 0; it < 2; ++it) {
      const int c = (it * 256 + tid) * 8;
      gload_lds16(&Kbh[kt * 4096 + c], &Ks[buf][(it * 256 + w * 64) * 8]);
      gload_lds16(&Vbh[kt * 4096 + c], &Vs[buf][(it * 256 + w * 64) * 8]);
    }
  };

  stage(0, 0);
  __syncthreads();
  int cur = 0;

  for (int kt = 0; kt < 16; ++kt) {
    if (kt < 15) stage(cur ^ 1, kt + 1);

    // S^T = K_tile (A) x Q (B); reads are base + lane*16B + imm (conflict-free)
    f32x16 s0 = {}, s1 = {};
    __builtin_amdgcn_s_setprio(1);
    #pragma unroll
    for (int m = 0; m < 4; ++m) {
      bf16x8 k0 = *reinterpret_cast<const bf16x8*>(&Ks[cur][m * 1024 + lane * 8]);
      bf16x8 k1 = *reinterpret_cast<const bf16x8*>(&Ks[cur][m * 1024 + 512 + lane * 8]);
      s0 = MFMA32(k0, qf[m], s0, 0, 0, 0);
      s1 = MFMA32(k1, qf[m], s1, 0, 0, 0);
    }
    __builtin_amdgcn_s_setprio(0);

    // P = exp2(S); pack to bf16; accumulate row-sum in-lane.
    unsigned W0[8], W1[8];
    #pragma unroll
    for (int j = 0; j < 8; ++j) {
      const int r = 4 * (j >> 1) + 2 * (j & 1);
      float pa0 = __builtin_amdgcn_exp2f(s0[r]);
      float pb0 = __builtin_amdgcn_exp2f(s0[r + 1]);
      float pa1 = __builtin_amdgcn_exp2f(s1[r]);
      float pb1 = __builtin_amdgcn_exp2f(s1[r + 1]);
      lr += (pa0 + pb0) + (pa1 + pb1);
      asm("v_cvt_pk_bf16_f32 %0, %1, %2" : "=v"(W0[j]) : "v"(pa0), "v"(pb0));
      asm("v_cvt_pk_bf16_f32 %0, %1, %2" : "=v"(W1[j]) : "v"(pa1), "v"(pb1));
    }

    // lane exchange: build PV A-fragments
    unsigned paw[4][4];
    #pragma unroll
    for (int ks = 0; ks < 4; ++ks) {
      const int ksl = ks & 1;
      #pragma unroll
      for (int p = 0; p < 2; ++p) {
        unsigned x = (ks < 2) ? W0[4 * ksl + p] : W1[4 * ksl + p];
        unsigned y = (ks < 2) ? W0[4 * ksl + 2 + p] : W1[4 * ksl + 2 + p];
        asm("v_permlane32_swap_b32 %0, %1" : "+v"(x), "+v"(y));
        paw[ks][p] = x;
        paw[ks][2 + p] = y;
      }
    }

    // O += P x V
    __builtin_amdgcn_s_setprio(1);
    #pragma unroll
    for (int ks = 0; ks < 4; ++ks) {
      bf16x8 pa = __builtin_bit_cast(bf16x8, u32x4{paw[ks][0], paw[ks][1], paw[ks][2], paw[ks][3]});
      bf16x8 v0 = *reinterpret_cast<const bf16x8*>(&Vs[cur][ks * 1024 + lane * 8]);
      bf16x8 v1 = *reinterpret_cast<const bf16x8*>(&Vs[cur][ks * 1024 + 512 + lane * 8]);
      o0 = MFMA32(pa, v0, o0, 0, 0, 0);
      o1 = MFMA32(pa, v1, o1, 0, 0, 0);
    }
    __builtin_amdgcn_s_setprio(0);

    __syncthreads();
    cur ^= 1;
  }

  float sum = lr + __shfl_xor(lr, 32);
  float rinv = 1.0f / sum;
  u16* aop = &AO[(size_t)(b * 1024 + q0) * 1024 + h * 64 + l32];
  #pragma unroll
  for (int r = 0; r < 16; ++r) {
    const int ql = (r & 3) + 8 * (r >> 2) + 4 * u;
    int ri_i = __builtin_amdgcn_ds_bpermute((ql + (u << 5)) << 2, __builtin_bit_cast(int, rinv));
    float ri = __builtin_bit_cast(float, ri_i);
    aop[(size_t)ql * 1024] = f2b(o0[r] * ri);
    aop[(size_t)ql * 1024 + 32] = f2b(o1[r] * ri);
  }
}

extern "C" void kernel_launch(void* const* d_in, const int* in_sizes, int n_in,
                              void* d_out, int out_size, void* d_ws, size_t ws_size,
                              hipStream_t stream) {
  const float* x   = (const float*)d_in[0];
  const float* ctx = (const float*)d_in[1];
  const float* Wq  = (const float*)d_in[2];
  const float* bq  = (const float*)d_in[3];
  const float* Wk  = (const float*)d_in[4];
  const float* bk  = (const float*)d_in[5];
  const float* Wv  = (const float*)d_in[6];
  const float* bv  = (const float*)d_in[7];
  const float* Wo  = (const float*)d_in[8];
  const float* bo  = (const float*)d_in[9];
  float* out = (float*)d_out;
  char* ws = (char*)d_ws;

  u16* xb  = (u16*)(ws + (size_t)0);          // 16MB (also reused as AO)
  u16* cb  = (u16*)(ws + ((size_t)16 << 20));
  u16* Qb  = (u16*)(ws + ((size_t)32 << 20));
  u16* Kf  = (u16*)(ws + ((size_t)48 << 20));
  u16* Vf  = (u16*)(ws + ((size_t)64 << 20));
  u16* Wqt = (u16*)(ws + ((size_t)80 << 20));
  u16* Wkt = (u16*)(ws + ((size_t)82 << 20));
  u16* Wvt = (u16*)(ws + ((size_t)84 << 20));
  u16* Wot = (u16*)(ws + ((size_t)86 << 20));

  prep<<<dim3(8192, 1, 3), 256, 0, stream>>>(x, ctx, xb, cb, Wq, Wk, Wv, Wo, Wqt, Wkt, Wvt, Wot);
  gemm_qkv<<<dim3(64, 8, 3), 256, 0, stream>>>(xb, cb, Wqt, Wkt, Wvt, bq, bk, bv, Qb, Kf, Vf);
  attn2<<<dim3(1024), 256, 0, stream>>>(Qb, Kf, Vf, xb /*AO*/);
  gemm_o<<<dim3(64, 8), 256, 0, stream>>>(xb, Wot, bo, out);
}